// Round 8
// baseline (1758.339 us; speedup 1.0000x reference)
//
#include <hip/hip_runtime.h>
#include <math.h>

// CTRNN + adaptive DOPRI5 (B=2048, N=1024). Round 8: persistent kernel,
// 256 blocks x 512 thr, block owns 256 rows x 32 cols (rowgroup = bid&7,
// XCD-local act exchange). Changes vs r7 (which was 97% stall-bound):
//  - ALL barriers are contention-free flag arrays (one 64B line per block,
//    parallel-lane polling, zero RMW). Grid sync fused with a two-level
//    deterministic error reduction (no atomicAdd).
//  - W tile (64KB fp16) lives in LDS for the whole kernel -> no per-iter
//    divergent L2 gathers in the GEMM inner loop.
//  - k2..k5, k1/k7, err, drive in packed half2 registers (kLs LDS freed).

typedef float f4 __attribute__((ext_vector_type(4)));
typedef float f32x4 __attribute__((ext_vector_type(4)));
typedef _Float16 half8v __attribute__((ext_vector_type(8)));
typedef _Float16 half4v __attribute__((ext_vector_type(4)));
typedef _Float16 half2v __attribute__((ext_vector_type(2)));

#define AS1 __attribute__((address_space(1)))
#define AS3 __attribute__((address_space(3)))

#define NBLK 256
#define NTHR 512
#define TOTD (2048.0 * 1024.0)

#define E1c (71.0f / 57600.0f)
#define E3c (-71.0f / 16695.0f)
#define E4c (71.0f / 1920.0f)
#define E5c (-17253.0f / 339200.0f)
#define E6c (22.0f / 525.0f)
#define E7c (-1.0f / 40.0f)

#define ALD(p) __hip_atomic_load((p), __ATOMIC_ACQUIRE, __HIP_MEMORY_SCOPE_AGENT)
#define AST(p, v) __hip_atomic_store((p), (v), __ATOMIC_RELEASE, __HIP_MEMORY_SCOPE_AGENT)
#define RLD(p) __hip_atomic_load((p), __ATOMIC_RELAXED, __HIP_MEMORY_SCOPE_AGENT)
#define RST(p, v) __hip_atomic_store((p), (v), __ATOMIC_RELAXED, __HIP_MEMORY_SCOPE_AGENT)

// ws scalar layout (ints): flg[256*16] @0, rgf[8*16] @4096, rgs[8*16] @4224,
// part[256*16] @4352 -> total 8448 ints = 33792 B < 64KB.
__global__ void k_zero(int* w) {
  int i = blockIdx.x * blockDim.x + threadIdx.x;
  if (i < 8448) w[i] = 0;
}

__device__ __forceinline__ float ftanh(float x) {
  x = fminf(fmaxf(x, -9.0f), 9.0f);
  float e = __expf(2.0f * x);
  return (e - 1.0f) / (e + 1.0f);
}

// rowgroup barrier: 32 blocks (bid = rg + 8*i), flag-per-block, no RMW.
__device__ __forceinline__ void rowbar(int* flg, int bid, int rg, int e) {
  __syncthreads();
  if (threadIdx.x < 64) {
    if (threadIdx.x == 0) { __threadfence(); AST(&flg[bid * 16], e); }
    if (threadIdx.x < 32) {
      while (ALD(&flg[(rg + 8 * (int)threadIdx.x) * 16]) < e)
        __builtin_amdgcn_s_sleep(1);
    }
  }
  __syncthreads();
  __threadfence();
}

// grid sync + deterministic two-level sum of per-block partials.
__device__ __forceinline__ double gred(int* flg, int* rgf, int* rgs, int* part,
                                       int bid, int rg, int e, float sblk,
                                       float* bcv) {
  if (threadIdx.x == 0) {
    __threadfence();
    RST(&part[bid * 16], __float_as_int(sblk));
    __threadfence();
    AST(&flg[bid * 16], e);
  }
  if (bid == rg) {  // one leader per rowgroup
    if (threadIdx.x < 32) {
      while (ALD(&flg[(rg + 8 * (int)threadIdx.x) * 16]) < e)
        __builtin_amdgcn_s_sleep(1);
    }
    if (threadIdx.x < 64) {
      float v = 0.0f;
      if (threadIdx.x < 32)
        v = __int_as_float(RLD(&part[(rg + 8 * (int)threadIdx.x) * 16]));
#pragma unroll
      for (int o = 32; o > 0; o >>= 1) v += __shfl_down(v, o, 64);
      if (threadIdx.x == 0) {
        RST(&rgs[rg * 16], __float_as_int(v));
        __threadfence();
        AST(&rgf[rg * 16], e);
      }
    }
  }
  if (threadIdx.x < 8) {
    while (ALD(&rgf[(int)threadIdx.x * 16]) < e) __builtin_amdgcn_s_sleep(1);
  }
  if (threadIdx.x < 64) {
    float sv = 0.0f;
    if (threadIdx.x < 8) sv = __int_as_float(RLD(&rgs[(int)threadIdx.x * 16]));
#pragma unroll
    for (int o = 4; o > 0; o >>= 1) sv += __shfl_down(sv, o, 64);
    if (threadIdx.x == 0) *bcv = sv;
  }
  __syncthreads();
  __threadfence();
  return (double)*bcv;
}

// rec tile [256x32] = act[256,1024] @ W[32,1024]^T. act double-buffered
// through LDS (global_load_lds, pre-swizzled source); W from LDS-resident
// swizzled tile (loaded once in the kernel prologue).
__device__ __forceinline__ void gemm(const _Float16* __restrict__ act,
                                     _Float16* As, const _Float16* Ws,
                                     int rowBase, int tid, int wv, int lr, int lk,
                                     f32x4 acc[2][2]) {
#pragma unroll
  for (int m = 0; m < 2; ++m)
#pragma unroll
    for (int n = 0; n < 2; ++n)
#pragma unroll
      for (int q = 0; q < 4; ++q) acc[m][n][q] = 0.0f;
#pragma unroll
  for (int u = 0; u < 4; ++u) {
    int slot = u * NTHR + tid;
    int row = slot >> 3, ch = slot & 7;
    __builtin_amdgcn_global_load_lds(
        (const AS1 void*)(act + (size_t)(rowBase + row) * 1024 + ((ch ^ (row & 7)) << 3)),
        (AS3 void*)(As + slot * 8), 16, 0, 0);
  }
#pragma unroll 1
  for (int it = 0; it < 16; ++it) {
    __syncthreads();
    const _Float16* Ac = As + (it & 1) * 16384;
    if (it < 15) {
      _Float16* An = As + ((it + 1) & 1) * 16384;
      int k0n = (it + 1) << 6;
#pragma unroll
      for (int u = 0; u < 4; ++u) {
        int slot = u * NTHR + tid;
        int row = slot >> 3, ch = slot & 7;
        __builtin_amdgcn_global_load_lds(
            (const AS1 void*)(act + (size_t)(rowBase + row) * 1024 + k0n + ((ch ^ (row & 7)) << 3)),
            (AS3 void*)(An + slot * 8), 16, 0, 0);
      }
    }
    half8v bf[2][2];
#pragma unroll
    for (int n = 0; n < 2; ++n) {
      int lc = n * 16 + lr;
#pragma unroll
      for (int ks = 0; ks < 2; ++ks) {
        int ch = it * 8 + ((ks * 4 + lk) ^ (lc & 7));
        bf[n][ks] = *(const half8v*)(Ws + lc * 1024 + ch * 8);
      }
    }
    half8v af[2][2];
#pragma unroll
    for (int m = 0; m < 2; ++m) {
      int row = wv * 32 + m * 16 + lr;
#pragma unroll
      for (int ks = 0; ks < 2; ++ks)
        af[m][ks] = *(const half8v*)(Ac + row * 64 + (((ks * 4 + lk) ^ (row & 7)) << 3));
    }
#pragma unroll
    for (int ks = 0; ks < 2; ++ks)
#pragma unroll
      for (int m = 0; m < 2; ++m)
#pragma unroll
        for (int n = 0; n < 2; ++n)
          acc[m][n] = __builtin_amdgcn_mfma_f32_16x16x32_f16(af[m][ks], bf[n][ks], acc[m][n], 0, 0, 0);
  }
}

// Stage-S epilogue; e = m*8 + j*2 + n; packed half2 state.
template <int S>
__device__ __forceinline__ void stage_epi(
    const f32x4 acc[2][2], float h,
    const float* y, float* ys, const half2v* dh,
    half2v* k1h, half2v* kh2, half2v* kh3, half2v* kh4, half2v* kh5, half2v* eh,
    const float* itau2, const float* bias2,
    _Float16* __restrict__ actOut, int rowBase, int colBase,
    int wv, int lr, int lk, float* errAcc) {
#pragma unroll
  for (int m = 0; m < 2; ++m) {
#pragma unroll
    for (int j = 0; j < 4; ++j) {
#pragma unroll
      for (int n = 0; n < 2; ++n) {
        const int e = m * 8 + j * 2 + n;
        float yv = y[e];
        float ks;
        if constexpr (S == 1) {
          ks = (float)k1h[e >> 1][e & 1];
        } else {
          ks = itau2[n] * ((float)dh[e >> 1][e & 1] + acc[m][n][j] - ys[e]);
        }
        float nys;
        if constexpr (S == 1) {
          eh[e >> 1][e & 1] = (_Float16)(E1c * ks);
          nys = yv + h * (0.2f * ks);
        } else if constexpr (S == 2) {
          kh2[e >> 1][e & 1] = (_Float16)ks;
          float k1 = (float)k1h[e >> 1][e & 1];
          nys = yv + h * ((3.0f / 40.0f) * k1 + (9.0f / 40.0f) * ks);
        } else if constexpr (S == 3) {
          kh3[e >> 1][e & 1] = (_Float16)ks;
          eh[e >> 1][e & 1] = (_Float16)((float)eh[e >> 1][e & 1] + E3c * ks);
          float k1 = (float)k1h[e >> 1][e & 1], k2 = (float)kh2[e >> 1][e & 1];
          nys = yv + h * ((44.0f / 45.0f) * k1 + (-56.0f / 15.0f) * k2 + (32.0f / 9.0f) * ks);
        } else if constexpr (S == 4) {
          kh4[e >> 1][e & 1] = (_Float16)ks;
          eh[e >> 1][e & 1] = (_Float16)((float)eh[e >> 1][e & 1] + E4c * ks);
          float k1 = (float)k1h[e >> 1][e & 1], k2 = (float)kh2[e >> 1][e & 1];
          float k3 = (float)kh3[e >> 1][e & 1];
          nys = yv + h * ((19372.0f / 6561.0f) * k1 + (-25360.0f / 2187.0f) * k2 +
                          (64448.0f / 6561.0f) * k3 + (-212.0f / 729.0f) * ks);
        } else if constexpr (S == 5) {
          kh5[e >> 1][e & 1] = (_Float16)ks;
          eh[e >> 1][e & 1] = (_Float16)((float)eh[e >> 1][e & 1] + E5c * ks);
          float k1 = (float)k1h[e >> 1][e & 1], k2 = (float)kh2[e >> 1][e & 1];
          float k3 = (float)kh3[e >> 1][e & 1], k4 = (float)kh4[e >> 1][e & 1];
          nys = yv + h * ((9017.0f / 3168.0f) * k1 + (-355.0f / 33.0f) * k2 +
                          (46732.0f / 5247.0f) * k3 + (49.0f / 176.0f) * k4 +
                          (-5103.0f / 18656.0f) * ks);
        } else if constexpr (S == 6) {
          eh[e >> 1][e & 1] = (_Float16)((float)eh[e >> 1][e & 1] + E6c * ks);
          float k1 = (float)k1h[e >> 1][e & 1];
          float k3 = (float)kh3[e >> 1][e & 1], k4 = (float)kh4[e >> 1][e & 1];
          float k5 = (float)kh5[e >> 1][e & 1];
          nys = yv + h * ((35.0f / 384.0f) * k1 + (500.0f / 1113.0f) * k3 +
                          (125.0f / 192.0f) * k4 + (-2187.0f / 6784.0f) * k5 +
                          (11.0f / 84.0f) * ks);
        } else {  // S == 7: k7 -> kh2 slot (k2 dead after S5); error norm
          kh2[e >> 1][e & 1] = (_Float16)ks;
          float ev = h * ((float)eh[e >> 1][e & 1] + E7c * ks);
          float sc = 1e-6f + 1e-3f * fmaxf(fabsf(yv), fabsf(ys[e]));
          float r = ev / sc;
          *errAcc += r * r;
          nys = 0.0f;
        }
        if constexpr (S <= 6) {
          ys[e] = nys;
          int row = rowBase + wv * 32 + m * 16 + lk * 4 + j;
          int col = colBase + n * 16 + lr;
          actOut[(size_t)row * 1024 + col] = (_Float16)ftanh(nys + bias2[n]);
        }
      }
    }
  }
}

__global__ __launch_bounds__(NTHR) void k_ode(
    const float* __restrict__ inp, const float* __restrict__ prev,
    const float* __restrict__ tau, const f4* __restrict__ W4,
    const float* __restrict__ iw, const float* __restrict__ bias,
    float* __restrict__ out, int* __restrict__ wsi,
    _Float16* __restrict__ Wh, _Float16* __restrict__ ab0,
    _Float16* __restrict__ ab1) {
  __shared__ _Float16 Ws[32 * 1024];     // 64 KB W tile (kernel-lifetime)
  __shared__ _Float16 As[2 * 2048 * 8];  // 64 KB act double-buffer
  __shared__ float wsum[8];
  __shared__ float bcv;

  int* flg = wsi;
  int* rgf = wsi + 4096;
  int* rgs = wsi + 4224;
  int* part = wsi + 4352;

  const int tid = (int)threadIdx.x, bid = (int)blockIdx.x;
  const int lane = tid & 63, wv = tid >> 6;
  const int lr = lane & 15, lk = lane >> 4;
  const int rg = bid & 7, cg = bid >> 3;
  const int rowBase = rg * 256, colBase = cg * 32;

  // --- W -> fp16 cast (each block its 4096-float slice) ---
  {
    half4v* Wh4 = (half4v*)Wh;
#pragma unroll
    for (int u = 0; u < 2; ++u) {
      int idx = bid * 1024 + u * NTHR + tid;
      f4 w = W4[idx];
      half4v o;
#pragma unroll
      for (int j = 0; j < 4; ++j) o[j] = (_Float16)w[j];
      Wh4[idx] = o;
    }
  }

  // --- state init + act1 -> ab1 ---
  float y[16], ysr[16];
  half2v dh[8], k1h[8], kh2[8], kh3[8], kh4[8], kh5[8], eh[8];
  float itau2[2], bias2[2];
#pragma unroll
  for (int n = 0; n < 2; ++n) {
    int col = colBase + n * 16 + lr;
    itau2[n] = 1.0f / tau[col];
    bias2[n] = bias[col];
  }
#pragma unroll
  for (int m = 0; m < 2; ++m)
#pragma unroll
    for (int j = 0; j < 4; ++j)
#pragma unroll
      for (int n = 0; n < 2; ++n) {
        const int e = m * 8 + j * 2 + n;
        int row = rowBase + wv * 32 + m * 16 + lk * 4 + j;
        int col = colBase + n * 16 + lr;
        size_t off = (size_t)row * 1024 + col;
        float yv = prev[off];
        y[e] = yv;
        ysr[e] = yv;
        dh[e >> 1][e & 1] = (_Float16)(inp[off] * iw[col]);
        ab1[off] = (_Float16)ftanh(yv + bias2[n]);
      }

  int pe = 1;
  gred(flg, rgf, rgs, part, bid, rg, pe, 0.0f, &bcv);  // Wh + act1 visible

  // --- W tile -> LDS (once; swizzled via pre-swizzled source) ---
#pragma unroll
  for (int u = 0; u < 8; ++u) {
    int slot = u * NTHR + tid;          // 0..4095
    int lc = slot >> 7, ch = slot & 127;
    __builtin_amdgcn_global_load_lds(
        (const AS1 void*)(Wh + (size_t)(colBase + lc) * 1024 + ((ch ^ (lc & 7)) << 3)),
        (AS3 void*)(Ws + slot * 8), 16, 0, 0);
  }

  f32x4 acc[2][2];
  gemm(ab1, As, Ws, rowBase, tid, wv, lr, lk, acc);  // initial k1 (drains Ws loads too)
#pragma unroll
  for (int m = 0; m < 2; ++m)
#pragma unroll
    for (int j = 0; j < 4; ++j)
#pragma unroll
      for (int n = 0; n < 2; ++n) {
        const int e = m * 8 + j * 2 + n;
        k1h[e >> 1][e & 1] =
            (_Float16)(itau2[n] * ((float)dh[e >> 1][e & 1] + acc[m][n][j] - y[e]));
      }

  float t = 0.0f, dtv = 0.1f;
#pragma unroll 1
  for (int s = 0; s < 40; ++s) {
    if (t >= 1.0f - 1e-7f) break;
    const float h = fminf(dtv, 1.0f - t);

    stage_epi<1>(acc, h, y, ysr, dh, k1h, kh2, kh3, kh4, kh5, eh, itau2, bias2,
                 ab0, rowBase, colBase, wv, lr, lk, nullptr);
    rowbar(flg, bid, rg, ++pe);
    gemm(ab0, As, Ws, rowBase, tid, wv, lr, lk, acc);

    stage_epi<2>(acc, h, y, ysr, dh, k1h, kh2, kh3, kh4, kh5, eh, itau2, bias2,
                 ab1, rowBase, colBase, wv, lr, lk, nullptr);
    rowbar(flg, bid, rg, ++pe);
    gemm(ab1, As, Ws, rowBase, tid, wv, lr, lk, acc);

    stage_epi<3>(acc, h, y, ysr, dh, k1h, kh2, kh3, kh4, kh5, eh, itau2, bias2,
                 ab0, rowBase, colBase, wv, lr, lk, nullptr);
    rowbar(flg, bid, rg, ++pe);
    gemm(ab0, As, Ws, rowBase, tid, wv, lr, lk, acc);

    stage_epi<4>(acc, h, y, ysr, dh, k1h, kh2, kh3, kh4, kh5, eh, itau2, bias2,
                 ab1, rowBase, colBase, wv, lr, lk, nullptr);
    rowbar(flg, bid, rg, ++pe);
    gemm(ab1, As, Ws, rowBase, tid, wv, lr, lk, acc);

    stage_epi<5>(acc, h, y, ysr, dh, k1h, kh2, kh3, kh4, kh5, eh, itau2, bias2,
                 ab0, rowBase, colBase, wv, lr, lk, nullptr);
    rowbar(flg, bid, rg, ++pe);
    gemm(ab0, As, Ws, rowBase, tid, wv, lr, lk, acc);

    stage_epi<6>(acc, h, y, ysr, dh, k1h, kh2, kh3, kh4, kh5, eh, itau2, bias2,
                 ab1, rowBase, colBase, wv, lr, lk, nullptr);
    rowbar(flg, bid, rg, ++pe);
    gemm(ab1, As, Ws, rowBase, tid, wv, lr, lk, acc);

    float errAcc = 0.0f;
    stage_epi<7>(acc, h, y, ysr, dh, k1h, kh2, kh3, kh4, kh5, eh, itau2, bias2,
                 nullptr, rowBase, colBase, wv, lr, lk, &errAcc);
#pragma unroll
    for (int o = 32; o > 0; o >>= 1) errAcc += __shfl_down(errAcc, o, 64);
    if (lane == 0) wsum[wv] = errAcc;
    __syncthreads();
    float sblk = 0.0f;
    if (tid == 0) {
#pragma unroll
      for (int w = 0; w < 8; ++w) sblk += wsum[w];
    }
    double sd = gred(flg, rgf, rgs, part, bid, rg, ++pe, sblk, &bcv);

    float enorm = fmaxf(sqrtf((float)(sd / TOTD)), 1e-10f);
    if (enorm <= 1.0f) {
      t = t + h;
#pragma unroll
      for (int e = 0; e < 16; ++e) y[e] = ysr[e];
#pragma unroll
      for (int i = 0; i < 8; ++i) k1h[i] = kh2[i];  // FSAL: k1 = k7
    }
    float factor = fminf(fmaxf(0.9f * powf(enorm, -0.2f), 0.2f), 5.0f);
    dtv = dtv * factor;
  }

  // --- final output ---
#pragma unroll
  for (int m = 0; m < 2; ++m)
#pragma unroll
    for (int j = 0; j < 4; ++j)
#pragma unroll
      for (int n = 0; n < 2; ++n) {
        const int e = m * 8 + j * 2 + n;
        int row = rowBase + wv * 32 + m * 16 + lk * 4 + j;
        int col = colBase + n * 16 + lr;
        out[(size_t)row * 1024 + col] = y[e];
      }
}

extern "C" void kernel_launch(void* const* d_in, const int* in_sizes, int n_in,
                              void* d_out, int out_size, void* d_ws, size_t ws_size,
                              hipStream_t stream) {
  const float* inp = (const float*)d_in[0];
  const float* prev = (const float*)d_in[1];
  const float* tau = (const float*)d_in[2];
  const f4* W4 = (const f4*)d_in[3];
  const float* iw = (const float*)d_in[4];
  const float* bias = (const float*)d_in[5];
  float* out = (float*)d_out;

  char* ws = (char*)d_ws;
  const size_t MB = 1024 * 1024;
  int* wsi = (int*)ws;                                   // flags/partials
  _Float16* Wh = (_Float16*)(ws + 64 * 1024);            // 2 MB
  _Float16* ab0 = (_Float16*)(ws + 64 * 1024 + 2 * MB);  // 4 MB
  _Float16* ab1 = (_Float16*)(ws + 64 * 1024 + 6 * MB);  // 4 MB

  k_zero<<<17, 512, 0, stream>>>(wsi);
  k_ode<<<NBLK, NTHR, 0, stream>>>(inp, prev, tau, W4, iw, bias, out,
                                   wsi, Wh, ab0, ab1);
}

// Round 9
// 1562.319 us; speedup vs baseline: 1.1255x; 1.1255x over previous
//
#include <hip/hip_runtime.h>
#include <math.h>

// CTRNN + adaptive DOPRI5 (B=2048, N=1024). Round 9: ZERO inter-block data
// exchange. Batch rows are independent ODEs; 256 blocks x 8 complete rows.
// act (8x1024 fp16) lives in block-local LDS (ping-pong); W (2MB fp16,
// L2-replicated read-only) is streamed per GEMM. The ONLY inter-block
// communication is one 8-byte packed (epoch|errpartial) flag per block per
// step, alternating 2 slots, reduced deterministically in every block.
// MFMA M=8 via row-duplication (A row = lane&7); dup C rows give each
// element to 2 lanes -> lanes<32 own col-tiles 0..3, lanes>=32 own 4..7.

typedef float f4 __attribute__((ext_vector_type(4)));
typedef float f32x4 __attribute__((ext_vector_type(4)));
typedef _Float16 half8v __attribute__((ext_vector_type(8)));
typedef _Float16 half4v __attribute__((ext_vector_type(4)));
typedef _Float16 half2v __attribute__((ext_vector_type(2)));

#define NBLK 256
#define NTHR 512

#define E1c (71.0f / 57600.0f)
#define E3c (-71.0f / 16695.0f)
#define E4c (71.0f / 1920.0f)
#define E5c (-17253.0f / 339200.0f)
#define E6c (22.0f / 525.0f)
#define E7c (-1.0f / 40.0f)

typedef unsigned long long u64;

#define ALD64(p) __hip_atomic_load((p), __ATOMIC_ACQUIRE, __HIP_MEMORY_SCOPE_AGENT)
#define AST64(p, v) __hip_atomic_store((p), (v), __ATOMIC_RELEASE, __HIP_MEMORY_SCOPE_AGENT)

__global__ void k_zero(u64* pk) {
  int i = blockIdx.x * blockDim.x + threadIdx.x;
  if (i < 2048) pk[i] = 0ull;
}

__device__ __forceinline__ float ftanh(float x) {
  x = fminf(fmaxf(x, -9.0f), 9.0f);
  float e = __expf(2.0f * x);
  return (e - 1.0f) / (e + 1.0f);
}

// acc[8]: col-tiles ct*16 within this wave's 128-col slice.
// A from LDS (row = lane&7, XOR-swizzled); B streamed from global Wh.
__device__ __forceinline__ void gemm8(const char* actB, const _Float16* wbase,
                                      int l, f32x4 acc[8]) {
#pragma unroll
  for (int ct = 0; ct < 8; ++ct)
#pragma unroll
    for (int q = 0; q < 4; ++q) acc[ct][q] = 0.0f;
  const int r = l & 7, lk = l >> 4;
  const char* arow = actB + r * 2048;
#pragma unroll 2
  for (int kb = 0; kb < 32; ++kb) {
    half8v a = *(const half8v*)(arow + ((((kb << 2) | lk) ^ r) << 4));
    const _Float16* wk = wbase + (kb << 5);
#pragma unroll
    for (int ct = 0; ct < 8; ++ct) {
      half8v b = *(const half8v*)(wk + ct * 16384);
      acc[ct] = __builtin_amdgcn_mfma_f32_16x16x32_f16(a, b, acc[ct], 0, 0, 0);
    }
  }
}

// e = ci*4 + q. Thread owns rows ((l>>4)&1)*4+q, cols wv*128+((l>>5)*4+ci)*16+(l&15).
template <int S>
__device__ __forceinline__ void stage_epi(
    const f32x4 acc[8], float h,
    float* y, float* ys, const half2v* dh,
    half2v* k1h, half2v* k2h, half2v* k3h, half2v* k4h, half2v* k5h, half2v* eh,
    const float* itau4, const float* bias4,
    char* actOut, int wv, int l, float* errAcc) {
  f32x4 sa[4];
  if (l >= 32) { sa[0] = acc[4]; sa[1] = acc[5]; sa[2] = acc[6]; sa[3] = acc[7]; }
  else         { sa[0] = acc[0]; sa[1] = acc[1]; sa[2] = acc[2]; sa[3] = acc[3]; }
#pragma unroll
  for (int ci = 0; ci < 4; ++ci) {
#pragma unroll
    for (int q = 0; q < 4; ++q) {
      const int e = ci * 4 + q;
      float yv = y[e];
      float ks;
      if constexpr (S == 1) {
        ks = (float)k1h[e >> 1][e & 1];
      } else {
        ks = itau4[ci] * ((float)dh[e >> 1][e & 1] + sa[ci][q] - ys[e]);
      }
      float nys;
      if constexpr (S == 1) {
        eh[e >> 1][e & 1] = (_Float16)(E1c * ks);
        nys = yv + h * (0.2f * ks);
      } else if constexpr (S == 2) {
        k2h[e >> 1][e & 1] = (_Float16)ks;
        float k1 = (float)k1h[e >> 1][e & 1];
        nys = yv + h * ((3.0f / 40.0f) * k1 + (9.0f / 40.0f) * ks);
      } else if constexpr (S == 3) {
        k3h[e >> 1][e & 1] = (_Float16)ks;
        eh[e >> 1][e & 1] = (_Float16)((float)eh[e >> 1][e & 1] + E3c * ks);
        float k1 = (float)k1h[e >> 1][e & 1], k2 = (float)k2h[e >> 1][e & 1];
        nys = yv + h * ((44.0f / 45.0f) * k1 + (-56.0f / 15.0f) * k2 + (32.0f / 9.0f) * ks);
      } else if constexpr (S == 4) {
        k4h[e >> 1][e & 1] = (_Float16)ks;
        eh[e >> 1][e & 1] = (_Float16)((float)eh[e >> 1][e & 1] + E4c * ks);
        float k1 = (float)k1h[e >> 1][e & 1], k2 = (float)k2h[e >> 1][e & 1];
        float k3 = (float)k3h[e >> 1][e & 1];
        nys = yv + h * ((19372.0f / 6561.0f) * k1 + (-25360.0f / 2187.0f) * k2 +
                        (64448.0f / 6561.0f) * k3 + (-212.0f / 729.0f) * ks);
      } else if constexpr (S == 5) {
        k5h[e >> 1][e & 1] = (_Float16)ks;
        eh[e >> 1][e & 1] = (_Float16)((float)eh[e >> 1][e & 1] + E5c * ks);
        float k1 = (float)k1h[e >> 1][e & 1], k2 = (float)k2h[e >> 1][e & 1];
        float k3 = (float)k3h[e >> 1][e & 1], k4 = (float)k4h[e >> 1][e & 1];
        nys = yv + h * ((9017.0f / 3168.0f) * k1 + (-355.0f / 33.0f) * k2 +
                        (46732.0f / 5247.0f) * k3 + (49.0f / 176.0f) * k4 +
                        (-5103.0f / 18656.0f) * ks);
      } else if constexpr (S == 6) {
        eh[e >> 1][e & 1] = (_Float16)((float)eh[e >> 1][e & 1] + E6c * ks);
        float k1 = (float)k1h[e >> 1][e & 1];
        float k3 = (float)k3h[e >> 1][e & 1], k4 = (float)k4h[e >> 1][e & 1];
        float k5 = (float)k5h[e >> 1][e & 1];
        nys = yv + h * ((35.0f / 384.0f) * k1 + (500.0f / 1113.0f) * k3 +
                        (125.0f / 192.0f) * k4 + (-2187.0f / 6784.0f) * k5 +
                        (11.0f / 84.0f) * ks);
      } else {  // S == 7: k7 -> k2h slot (dead after S5); error norm
        k2h[e >> 1][e & 1] = (_Float16)ks;
        float ev = h * ((float)eh[e >> 1][e & 1] + E7c * ks);
        float sc = 1e-6f + 1e-3f * fmaxf(fabsf(yv), fabsf(ys[e]));
        float r = ev / sc;
        *errAcc += r * r;
        nys = 0.0f;
      }
      if constexpr (S <= 6) {
        ys[e] = nys;
        float av = ftanh(nys + bias4[ci]);
        int row = ((l >> 4) & 1) * 4 + q;
        int col = wv * 128 + ((l >> 5) * 4 + ci) * 16 + (l & 15);
        *(_Float16*)(actOut + row * 2048 + (((col >> 3) ^ row) << 4) + (col & 7) * 2) =
            (_Float16)av;
      }
    }
  }
}

__global__ __launch_bounds__(NTHR, 2) void k_ode(
    const float* __restrict__ inp, const float* __restrict__ prev,
    const float* __restrict__ tau, const f4* __restrict__ W4,
    const float* __restrict__ iw, const float* __restrict__ bias,
    float* __restrict__ out, u64* __restrict__ pk, _Float16* __restrict__ Wh) {
  __shared__ _Float16 actL[2][8][1024];   // 32 KB ping-pong act
  __shared__ float sm[256];
  __shared__ float wsum[8];
  __shared__ float bc;

  const int tid = (int)threadIdx.x, bid = (int)blockIdx.x;
  const int l = tid & 63, wv = tid >> 6;
  const int lr16 = l & 15, lk = l >> 4;
  const int rbase = bid * 8;
  char* A0 = (char*)&actL[0][0][0];
  char* A1 = (char*)&actL[1][0][0];

  // --- W -> fp16 cast (each block its 8KB slice) ---
  {
    half4v* Wh4 = (half4v*)Wh;
#pragma unroll
    for (int u = 0; u < 2; ++u) {
      int idx = bid * 1024 + u * NTHR + tid;
      f4 w = W4[idx];
      half4v o;
#pragma unroll
      for (int j = 0; j < 4; ++j) o[j] = (_Float16)w[j];
      Wh4[idx] = o;
    }
  }

  // --- per-thread state init + act1 -> A1 ---
  float y[16], ysr[16];
  half2v dh[8], k1h[8], k2h[8], k3h[8], k4h[8], k5h[8], eh[8];
  float itau4[4], bias4[4];
#pragma unroll
  for (int ci = 0; ci < 4; ++ci) {
    int col = wv * 128 + ((l >> 5) * 4 + ci) * 16 + lr16;
    itau4[ci] = 1.0f / tau[col];
    bias4[ci] = bias[col];
  }
#pragma unroll
  for (int ci = 0; ci < 4; ++ci)
#pragma unroll
    for (int q = 0; q < 4; ++q) {
      const int e = ci * 4 + q;
      int row = ((l >> 4) & 1) * 4 + q;
      int col = wv * 128 + ((l >> 5) * 4 + ci) * 16 + lr16;
      size_t off = (size_t)(rbase + row) * 1024 + col;
      float yv = prev[off];
      y[e] = yv;
      ysr[e] = yv;
      dh[e >> 1][e & 1] = (_Float16)(inp[off] * iw[col]);
      float av = ftanh(yv + bias4[ci]);
      *(_Float16*)(A1 + row * 2048 + (((col >> 3) ^ row) << 4) + (col & 7) * 2) =
          (_Float16)av;
    }

  // --- prologue sync: Wh visible everywhere (epoch 1, slot 1) ---
  __syncthreads();
  if (tid == 0) AST64(&pk[bid * 8 + 1], 1ull << 32);
  if (tid < 256) {
    while ((ALD64(&pk[tid * 8 + 1]) >> 32) < 1ull) __builtin_amdgcn_s_sleep(1);
  }
  __syncthreads();
  __threadfence();

  const _Float16* wbase = Wh + (size_t)(wv * 128 + lr16) * 1024 + lk * 8;
  f32x4 acc[8];

  // initial k1 = itau * (drive + W@act1 - y)
  gemm8(A1, wbase, l, acc);
  {
    f32x4 sa[4];
    if (l >= 32) { sa[0] = acc[4]; sa[1] = acc[5]; sa[2] = acc[6]; sa[3] = acc[7]; }
    else         { sa[0] = acc[0]; sa[1] = acc[1]; sa[2] = acc[2]; sa[3] = acc[3]; }
#pragma unroll
    for (int ci = 0; ci < 4; ++ci)
#pragma unroll
      for (int q = 0; q < 4; ++q) {
        const int e = ci * 4 + q;
        k1h[e >> 1][e & 1] =
            (_Float16)(itau4[ci] * ((float)dh[e >> 1][e & 1] + sa[ci][q] - y[e]));
      }
  }

  float t = 0.0f, dtv = 0.1f;
#pragma unroll 1
  for (int s = 0; s < 40; ++s) {
    if (t >= 1.0f - 1e-7f) break;
    const float h = fminf(dtv, 1.0f - t);

    stage_epi<1>(acc, h, y, ysr, dh, k1h, k2h, k3h, k4h, k5h, eh, itau4, bias4,
                 A0, wv, l, nullptr);
    __syncthreads();
    gemm8(A0, wbase, l, acc);
    stage_epi<2>(acc, h, y, ysr, dh, k1h, k2h, k3h, k4h, k5h, eh, itau4, bias4,
                 A1, wv, l, nullptr);
    __syncthreads();
    gemm8(A1, wbase, l, acc);
    stage_epi<3>(acc, h, y, ysr, dh, k1h, k2h, k3h, k4h, k5h, eh, itau4, bias4,
                 A0, wv, l, nullptr);
    __syncthreads();
    gemm8(A0, wbase, l, acc);
    stage_epi<4>(acc, h, y, ysr, dh, k1h, k2h, k3h, k4h, k5h, eh, itau4, bias4,
                 A1, wv, l, nullptr);
    __syncthreads();
    gemm8(A1, wbase, l, acc);
    stage_epi<5>(acc, h, y, ysr, dh, k1h, k2h, k3h, k4h, k5h, eh, itau4, bias4,
                 A0, wv, l, nullptr);
    __syncthreads();
    gemm8(A0, wbase, l, acc);
    stage_epi<6>(acc, h, y, ysr, dh, k1h, k2h, k3h, k4h, k5h, eh, itau4, bias4,
                 A1, wv, l, nullptr);   // act7 -> A1
    __syncthreads();
    gemm8(A1, wbase, l, acc);

    float errAcc = 0.0f;
    stage_epi<7>(acc, h, y, ysr, dh, k1h, k2h, k3h, k4h, k5h, eh, itau4, bias4,
                 nullptr, wv, l, &errAcc);
#pragma unroll
    for (int o = 32; o > 0; o >>= 1) errAcc += __shfl_down(errAcc, o, 64);
    if (l == 0) wsum[wv] = errAcc;
    __syncthreads();
    float sblk = 0.0f;
    if (tid == 0) {
#pragma unroll
      for (int w = 0; w < 8; ++w) sblk += wsum[w];
    }

    // --- the ONLY inter-block sync: packed (epoch|partial), 2 slots ---
    const u64 ep = (u64)(s + 2);
    const int slot = (int)(ep & 1);
    if (tid == 0)
      AST64(&pk[bid * 8 + slot], (ep << 32) | (u64)__float_as_uint(sblk));
    if (tid < 256) {
      u64 v;
      do {
        v = ALD64(&pk[tid * 8 + slot]);
      } while ((v >> 32) < ep);
      sm[tid] = __uint_as_float((unsigned)v);
    }
    __syncthreads();
    if (tid < 64) {
      float a = sm[tid] + sm[tid + 64] + sm[tid + 128] + sm[tid + 192];
#pragma unroll
      for (int o = 1; o < 64; o <<= 1) a += __shfl_xor(a, o, 64);
      if (tid == 0) bc = a;
    }
    __syncthreads();
    float sd = bc;

    float enorm = fmaxf(sqrtf(sd / 2097152.0f), 1e-10f);
    if (enorm <= 1.0f) {
      t = t + h;
#pragma unroll
      for (int e = 0; e < 16; ++e) y[e] = ysr[e];
#pragma unroll
      for (int i = 0; i < 8; ++i) k1h[i] = k2h[i];   // FSAL: k1 = k7
    }
    float factor = fminf(fmaxf(0.9f * powf(enorm, -0.2f), 0.2f), 5.0f);
    dtv = dtv * factor;
  }

  // --- final output ---
#pragma unroll
  for (int ci = 0; ci < 4; ++ci)
#pragma unroll
    for (int q = 0; q < 4; ++q) {
      const int e = ci * 4 + q;
      int row = ((l >> 4) & 1) * 4 + q;
      int col = wv * 128 + ((l >> 5) * 4 + ci) * 16 + lr16;
      out[(size_t)(rbase + row) * 1024 + col] = y[e];
    }
}

extern "C" void kernel_launch(void* const* d_in, const int* in_sizes, int n_in,
                              void* d_out, int out_size, void* d_ws, size_t ws_size,
                              hipStream_t stream) {
  const float* inp = (const float*)d_in[0];
  const float* prev = (const float*)d_in[1];
  const float* tau = (const float*)d_in[2];
  const f4* W4 = (const f4*)d_in[3];
  const float* iw = (const float*)d_in[4];
  const float* bias = (const float*)d_in[5];
  float* out = (float*)d_out;

  char* ws = (char*)d_ws;
  u64* pk = (u64*)ws;                          // 2048 u64 = 16 KB
  _Float16* Wh = (_Float16*)(ws + 64 * 1024);  // 2 MB

  k_zero<<<4, 512, 0, stream>>>(pk);
  k_ode<<<NBLK, NTHR, 0, stream>>>(inp, prev, tau, W4, iw, bias, out, pk, Wh);
}